// Round 1
// baseline (720.888 us; speedup 1.0000x reference)
//
#include <hip/hip_runtime.h>

// Problem constants
#define B_  2
#define S_  2048
#define D_  2048
#define H_  16
#define HD_ 128

typedef __attribute__((ext_vector_type(4))) float  f32x4;
typedef __attribute__((ext_vector_type(8))) short  short8;
typedef __attribute__((ext_vector_type(8))) __bf16 bf16x8;
typedef __attribute__((ext_vector_type(4))) float  floatv4;
typedef __attribute__((ext_vector_type(4))) unsigned short ushortv4;

// fp32 -> bf16 bits, round-to-nearest-even
__device__ inline unsigned short f2bf(float f) {
  unsigned int u = __builtin_bit_cast(unsigned int, f);
  u += 0x7fffu + ((u >> 16) & 1u);
  return (unsigned short)(u >> 16);
}

// async global->LDS, 16B per lane. lds must be wave-uniform base; data lands at base + lane*16.
__device__ inline void gld16(void* lds, const void* g) {
  __builtin_amdgcn_global_load_lds(
      (const __attribute__((address_space(1))) unsigned int*)g,
      (__attribute__((address_space(3))) unsigned int*)lds, 16, 0, 0);
}

__device__ inline bf16x8 lds_frag(const unsigned short* p) {
  return __builtin_bit_cast(bf16x8, *(const short8*)p);
}

// ---------------------------------------------------------------- converts
__global__ void cvt_bf16(const float* __restrict__ src, unsigned short* __restrict__ dst, int n4) {
  int i = blockIdx.x * 256 + threadIdx.x;
  if (i >= n4) return;
  floatv4 v = ((const floatv4*)src)[i];
  ushortv4 o;
  o.x = f2bf(v.x); o.y = f2bf(v.y); o.z = f2bf(v.z); o.w = f2bf(v.w);
  ((ushortv4*)dst)[i] = o;
}

// ---------------------------------------------------------------- GEMM (NT): C[m][n] = sum_k A[m][k]*W[n][k] + bias[n]
// A: MxK bf16 row-major, W: NxK bf16 row-major, C: MxN fp32. M,N,K multiples of 128/128/32.
__global__ __launch_bounds__(256, 2)
void gemm_nt(const unsigned short* __restrict__ A,
             const unsigned short* __restrict__ W,
             const float* __restrict__ bias,
             float* __restrict__ C, int M, int N, int K) {
  __shared__ __attribute__((aligned(16))) unsigned short As[128 * 32];
  __shared__ __attribute__((aligned(16))) unsigned short Bs[128 * 32];
  const int t = threadIdx.x;
  const int w = t >> 6, lane = t & 63;
  const int quad = lane >> 4, l16 = lane & 15;
  const int m0 = blockIdx.y * 128, n0 = blockIdx.x * 128;
  const int wm = (w >> 1) * 64, wn = (w & 1) * 64;   // wave quadrant: 64x64
  f32x4 acc[4][4] = {};

  for (int k0 = 0; k0 < K; k0 += 32) {
    __syncthreads();
#pragma unroll
    for (int j = 0; j < 2; ++j) {      // 8192 B per tile = 2 issues x 256 lanes x 16 B
      int o = (t + 256 * j) * 16;      // byte offset inside tile (row-major [128][32] bf16, 64 B/row)
      int row = o >> 6, cb = o & 63;
      gld16((char*)As + w * 1024 + j * 4096,
            (const char*)(A + (size_t)(m0 + row) * K + k0) + cb);
      gld16((char*)Bs + w * 1024 + j * 4096,
            (const char*)(W + (size_t)(n0 + row) * K + k0) + cb);
    }
    __syncthreads();
    bf16x8 af[4], bfr[4];
#pragma unroll
    for (int i = 0; i < 4; ++i)
      af[i] = lds_frag(As + (wm + i * 16 + l16) * 32 + quad * 8);
#pragma unroll
    for (int j = 0; j < 4; ++j)
      bfr[j] = lds_frag(Bs + (wn + j * 16 + l16) * 32 + quad * 8);
#pragma unroll
    for (int i = 0; i < 4; ++i)
#pragma unroll
      for (int j = 0; j < 4; ++j)
        acc[i][j] = __builtin_amdgcn_mfma_f32_16x16x32_bf16(af[i], bfr[j], acc[i][j], 0, 0, 0);
  }

#pragma unroll
  for (int j = 0; j < 4; ++j) {
    int col = n0 + wn + j * 16 + l16;
    float bv = bias[col];
#pragma unroll
    for (int i = 0; i < 4; ++i)
#pragma unroll
      for (int r = 0; r < 4; ++r) {
        int row = m0 + wm + i * 16 + quad * 4 + r;   // C/D: col=lane&15, row=quad*4+reg
        C[(size_t)row * N + col] = acc[i][j][r] + bv;
      }
  }
}

// ---------------------------------------------------------------- RoPE: Q,K (B,S,D) fp32 -> (B,H,S,HD); writes bf16 Q/K for attn + fp32 k output
__global__ void rope_kernel(const float* __restrict__ Qbuf,
                            const float* __restrict__ Kbuf,
                            const float* __restrict__ fc,
                            const float* __restrict__ fs,
                            unsigned short* __restrict__ Qa,
                            unsigned short* __restrict__ Ka,
                            float* __restrict__ k_out) {
  int idx = blockIdx.x * 256 + threadIdx.x;   // (b:1, s:11, h:4, i:6)
  int i = idx & 63;
  int h = (idx >> 6) & (H_ - 1);
  int s = (idx >> 10) & (S_ - 1);
  int b = idx >> 21;
  size_t src = ((size_t)(b * S_ + s)) * D_ + h * HD_ + 2 * i;
  float2 q = *(const float2*)(Qbuf + src);
  float2 k = *(const float2*)(Kbuf + src);
  float c = fc[s * 64 + i], sn = fs[s * 64 + i];
  float qor = q.x * c - q.y * sn, qoi = q.x * sn + q.y * c;
  float kor = k.x * c - k.y * sn, koi = k.x * sn + k.y * c;
  size_t dst = ((size_t)((b * H_ + h) * S_ + s)) * HD_ + 2 * i;
  *(unsigned int*)(Qa + dst) = (unsigned int)f2bf(qor) | ((unsigned int)f2bf(qoi) << 16);
  *(unsigned int*)(Ka + dst) = (unsigned int)f2bf(kor) | ((unsigned int)f2bf(koi) << 16);
  *(float2*)(k_out + dst) = make_float2(kor, koi);
}

// ---------------------------------------------------------------- V: (B,S,D) fp32 -> v_out (B,H,S,HD) fp32 + Vt (B,H,HD,S) bf16
__global__ void vtrans_kernel(const float* __restrict__ Vbuf,
                              float* __restrict__ v_out,
                              unsigned short* __restrict__ Vt) {
  __shared__ float tile[64][33];
  int t = threadIdx.x;
  int s0 = blockIdx.x * 64, d0 = blockIdx.y * 32, bh = blockIdx.z;
  int b = bh >> 4, h = bh & 15;
#pragma unroll
  for (int rr = 0; rr < 8; ++rr) {
    int sl = rr * 8 + (t >> 5), dl = t & 31;
    float v = Vbuf[((size_t)(b * S_ + s0 + sl)) * D_ + h * HD_ + d0 + dl];
    tile[sl][dl] = v;
    v_out[((size_t)(bh * S_ + s0 + sl)) * HD_ + d0 + dl] = v;
  }
  __syncthreads();
#pragma unroll
  for (int rr = 0; rr < 8; ++rr) {
    int dl = rr * 4 + (t >> 6), sl = t & 63;
    Vt[((size_t)(bh * HD_ + d0 + dl)) * S_ + s0 + sl] = f2bf(tile[sl][dl]);
  }
}

// ---------------------------------------------------------------- causal flash attention
// Qa,Ka: (B,H,S,HD) bf16 (roped); Vt: (B,H,HD,S) bf16; Oa: (B,S,D) bf16 out.
// Block: 64 q-rows (16 per wave), iterate 64-key tiles with online softmax.
__global__ __launch_bounds__(256, 2)
void attn_kernel(const unsigned short* __restrict__ Qa,
                 const unsigned short* __restrict__ Ka,
                 const unsigned short* __restrict__ Vt,
                 unsigned short* __restrict__ Oa) {
  __shared__ __attribute__((aligned(16))) unsigned short Qs[64 * 128];
  __shared__ __attribute__((aligned(16))) unsigned short Ks[64 * 128];
  __shared__ __attribute__((aligned(16))) unsigned short Vs[128 * 64];   // Vt tile: [d][n]
  __shared__ __attribute__((aligned(16))) unsigned short Ps[4][16 * 64]; // per-wave P (A-layout source)
  const int t = threadIdx.x, w = t >> 6, lane = t & 63;
  const int quad = lane >> 4, l16 = lane & 15;
  const int bh = blockIdx.y;
  const int b = bh >> 4, h = bh & 15;
  const int q0 = blockIdx.x * 64;
  const unsigned short* Qp = Qa + (size_t)bh * S_ * HD_;
  const unsigned short* Kp = Ka + (size_t)bh * S_ * HD_;
  const unsigned short* Vp = Vt + (size_t)bh * HD_ * S_;
  const float scale = 0.08838834764831845f;  // 1/sqrt(128)
  const float NEGINF = -__builtin_inff();

  // stage Q tile (64x128 bf16 = 16 KB): 4 issues
#pragma unroll
  for (int j = 0; j < 4; ++j) {
    int o = (t + 256 * j) * 16;
    int row = o >> 8, cb = o & 255;
    gld16((char*)Qs + w * 1024 + j * 4096,
          (const char*)(Qp + (size_t)(q0 + row) * HD_) + cb);
  }

  float m_i[4], l_i[4];
#pragma unroll
  for (int r = 0; r < 4; ++r) { m_i[r] = NEGINF; l_i[r] = 0.f; }
  f32x4 oacc[8] = {};

  const int qtile = q0 >> 6;
  for (int nt = 0; nt <= qtile; ++nt) {
    __syncthreads();   // prev tile's LDS reads done before restage (also orders Q staging on nt==0)
#pragma unroll
    for (int j = 0; j < 4; ++j) {      // K tile [64][128]
      int o = (t + 256 * j) * 16;
      int row = o >> 8, cb = o & 255;
      gld16((char*)Ks + w * 1024 + j * 4096,
            (const char*)(Kp + (size_t)(nt * 64 + row) * HD_) + cb);
    }
#pragma unroll
    for (int j = 0; j < 4; ++j) {      // Vt tile [128][64]
      int o = (t + 256 * j) * 16;
      int row = o >> 7, cb = o & 127;
      gld16((char*)Vs + w * 1024 + j * 4096,
            (const char*)(Vp + (size_t)row * S_ + nt * 64) + cb);
    }
    __syncthreads();   // drains vmcnt(0): staged data visible

    // --- S = Q K^T (wave's 16 q rows x 64 keys)
    f32x4 sacc[4] = {};
    bf16x8 qf[4];
#pragma unroll
    for (int kk = 0; kk < 4; ++kk)
      qf[kk] = lds_frag(Qs + (w * 16 + l16) * 128 + kk * 32 + quad * 8);
#pragma unroll
    for (int j = 0; j < 4; ++j)
#pragma unroll
      for (int kk = 0; kk < 4; ++kk) {
        bf16x8 kf = lds_frag(Ks + (j * 16 + l16) * 128 + kk * 32 + quad * 8);
        sacc[j] = __builtin_amdgcn_mfma_f32_16x16x32_bf16(qf[kk], kf, sacc[j], 0, 0, 0);
      }

    // --- scale + causal mask (diag tile only) + online softmax
    const int srow_base = q0 + w * 16 + quad * 4;
    const bool diag = (nt == qtile);
    float p[4][4], rowmax[4], rowsum[4], alpha[4];
#pragma unroll
    for (int r = 0; r < 4; ++r) rowmax[r] = NEGINF;
#pragma unroll
    for (int j = 0; j < 4; ++j) {
      int scol = nt * 64 + j * 16 + l16;
#pragma unroll
      for (int r = 0; r < 4; ++r) {
        float v = sacc[j][r] * scale;
        if (diag && scol > srow_base + r) v = NEGINF;
        p[j][r] = v;
        rowmax[r] = fmaxf(rowmax[r], v);
      }
    }
#pragma unroll
    for (int off = 1; off < 16; off <<= 1)
#pragma unroll
      for (int r = 0; r < 4; ++r) rowmax[r] = fmaxf(rowmax[r], __shfl_xor(rowmax[r], off));
#pragma unroll
    for (int r = 0; r < 4; ++r) {
      float mnew = fmaxf(m_i[r], rowmax[r]);
      alpha[r] = __expf(m_i[r] - mnew);   // first tile: exp(-inf)=0
      m_i[r] = mnew;
      rowsum[r] = 0.f;
    }
#pragma unroll
    for (int j = 0; j < 4; ++j)
#pragma unroll
      for (int r = 0; r < 4; ++r) {
        float e = __expf(p[j][r] - m_i[r]);   // masked: exp(-inf)=0
        p[j][r] = e;
        rowsum[r] += e;
      }
#pragma unroll
    for (int off = 1; off < 16; off <<= 1)
#pragma unroll
      for (int r = 0; r < 4; ++r) rowsum[r] += __shfl_xor(rowsum[r], off);
#pragma unroll
    for (int r = 0; r < 4; ++r) l_i[r] = l_i[r] * alpha[r] + rowsum[r];
#pragma unroll
    for (int f = 0; f < 8; ++f)
#pragma unroll
      for (int r = 0; r < 4; ++r) oacc[f][r] *= alpha[r];

    // --- P: C-layout regs -> per-wave LDS (bf16) -> A-layout frags
    unsigned short* Pw = &Ps[w][0];
#pragma unroll
    for (int j = 0; j < 4; ++j)
#pragma unroll
      for (int r = 0; r < 4; ++r)
        Pw[(quad * 4 + r) * 64 + j * 16 + l16] = f2bf(p[j][r]);
    asm volatile("s_waitcnt lgkmcnt(0)" ::: "memory");  // per-wave RAW on Ps

    // --- O += P V  (2 k-steps over 64 keys x 8 d-fragments)
#pragma unroll
    for (int s2 = 0; s2 < 2; ++s2) {
      bf16x8 pf = lds_frag(Pw + l16 * 64 + s2 * 32 + quad * 8);
#pragma unroll
      for (int f = 0; f < 8; ++f) {
        bf16x8 vf = lds_frag(Vs + (f * 16 + l16) * 64 + s2 * 32 + quad * 8);
        oacc[f] = __builtin_amdgcn_mfma_f32_16x16x32_bf16(pf, vf, oacc[f], 0, 0, 0);
      }
    }
  }

  // epilogue: O / l -> bf16 (B,S,D)
  float invl[4];
#pragma unroll
  for (int r = 0; r < 4; ++r) invl[r] = 1.f / l_i[r];
#pragma unroll
  for (int f = 0; f < 8; ++f)
#pragma unroll
    for (int r = 0; r < 4; ++r) {
      int srow = q0 + w * 16 + quad * 4 + r;
      int d = f * 16 + l16;
      Oa[((size_t)(b * S_ + srow)) * D_ + h * HD_ + d] = f2bf(oacc[f][r] * invl[r]);
    }
}

// ----------------------------------------------------------------
extern "C" void kernel_launch(void* const* d_in, const int* in_sizes, int n_in,
                              void* d_out, int out_size, void* d_ws, size_t ws_size,
                              hipStream_t stream) {
  const float* x    = (const float*)d_in[0];
  const float* wq_w = (const float*)d_in[1];
  const float* wq_b = (const float*)d_in[2];
  const float* wk_w = (const float*)d_in[3];
  const float* wk_b = (const float*)d_in[4];
  const float* wv_w = (const float*)d_in[5];
  const float* wv_b = (const float*)d_in[6];
  const float* wo_w = (const float*)d_in[7];
  const float* wo_b = (const float*)d_in[8];
  const float* fc   = (const float*)d_in[9];
  const float* fs   = (const float*)d_in[10];

  float* out = (float*)d_out;
  const size_t BSD = (size_t)B_ * S_ * D_;   // 8388608
  float* k_out = out + BSD;
  float* v_out = out + 2 * BSD;

  // workspace layout (151 MB total)
  char* ws = (char*)d_ws;
  unsigned short* xb   = (unsigned short*)(ws);              // x bf16          16.78 MB
  unsigned short* wqb  = (unsigned short*)(ws + 16777216);   // wq bf16          8.39 MB
  unsigned short* wkb  = (unsigned short*)(ws + 25165824);
  unsigned short* wvb  = (unsigned short*)(ws + 33554432);
  unsigned short* wob  = (unsigned short*)(ws + 41943040);
  float*          Vbuf = (float*)(ws + 50331648);            // V fp32 (B,S,D)  33.55 MB
  unsigned short* Qat  = (unsigned short*)(ws + 83886080);   // Q roped bf16 (B,H,S,HD)
  unsigned short* Kat  = (unsigned short*)(ws + 100663296);  // K roped bf16 (B,H,S,HD)
  unsigned short* Vt   = (unsigned short*)(ws + 117440512);  // V bf16 (B,H,HD,S)
  unsigned short* Ab   = (unsigned short*)(ws + 134217728);  // attn out bf16 (B,S,D)

  // fp32 Q/K intermediates borrow d_out regions (consumed before those regions' final writes)
  float* Qbuf = out;     // overwritten by final gemm (last)
  float* Kbuf = v_out;   // overwritten by vtrans (after rope consumed it)

  cvt_bf16<<<8192, 256, 0, stream>>>(x, xb, 2097152);
  cvt_bf16<<<4096, 256, 0, stream>>>(wq_w, wqb, 1048576);
  cvt_bf16<<<4096, 256, 0, stream>>>(wk_w, wkb, 1048576);
  cvt_bf16<<<4096, 256, 0, stream>>>(wv_w, wvb, 1048576);
  cvt_bf16<<<4096, 256, 0, stream>>>(wo_w, wob, 1048576);

  dim3 gg(16, 32);  // (N/128, M/128)
  gemm_nt<<<gg, 256, 0, stream>>>(xb, wqb, wq_b, Qbuf, 4096, 2048, 2048);
  gemm_nt<<<gg, 256, 0, stream>>>(xb, wkb, wk_b, Kbuf, 4096, 2048, 2048);
  gemm_nt<<<gg, 256, 0, stream>>>(xb, wvb, wv_b, Vbuf, 4096, 2048, 2048);

  rope_kernel<<<16384, 256, 0, stream>>>(Qbuf, Kbuf, fc, fs, Qat, Kat, k_out);
  vtrans_kernel<<<dim3(32, 4, 32), 256, 0, stream>>>(Vbuf, v_out, Vt);
  attn_kernel<<<dim3(32, 32), 256, 0, stream>>>(Qat, Kat, Vt, Ab);
  gemm_nt<<<gg, 256, 0, stream>>>(Ab, wob, wo_b, out, 4096, 2048, 2048);
}

// Round 2
// 561.967 us; speedup vs baseline: 1.2828x; 1.2828x over previous
//
#include <hip/hip_runtime.h>

// Problem constants
#define B_  2
#define S_  2048
#define D_  2048
#define H_  16
#define HD_ 128

// 1/sqrt(128) * log2(e): fold softmax scale AND exp->exp2 conversion into Q
#define QSCALE 0.1275174319003887f

typedef __attribute__((ext_vector_type(4))) float  f32x4;
typedef __attribute__((ext_vector_type(8))) short  short8;
typedef __attribute__((ext_vector_type(8))) __bf16 bf16x8;
typedef __attribute__((ext_vector_type(4))) float  floatv4;
typedef __attribute__((ext_vector_type(4))) unsigned short ushortv4;

// fp32 -> bf16 bits, round-to-nearest-even
__device__ inline unsigned short f2bf(float f) {
  unsigned int u = __builtin_bit_cast(unsigned int, f);
  u += 0x7fffu + ((u >> 16) & 1u);
  return (unsigned short)(u >> 16);
}

// async global->LDS, 16B per lane. lds must be wave-uniform base; data lands at base + lane*16.
__device__ inline void gld16(void* lds, const void* g) {
  __builtin_amdgcn_global_load_lds(
      (const __attribute__((address_space(1))) unsigned int*)g,
      (__attribute__((address_space(3))) unsigned int*)lds, 16, 0, 0);
}

__device__ inline bf16x8 lds_frag(const unsigned short* p) {
  return __builtin_bit_cast(bf16x8, *(const short8*)p);
}

// ---------------------------------------------------------------- converts
__global__ void cvt_bf16(const float* __restrict__ src, unsigned short* __restrict__ dst, int n4) {
  int i = blockIdx.x * 256 + threadIdx.x;
  if (i >= n4) return;
  floatv4 v = ((const floatv4*)src)[i];
  ushortv4 o;
  o.x = f2bf(v.x); o.y = f2bf(v.y); o.z = f2bf(v.z); o.w = f2bf(v.w);
  ((ushortv4*)dst)[i] = o;
}

// ---------------------------------------------------------------- GEMM (NT): C[m][n] = sum_k A[m][k]*W[n][k] + bias[n]
__global__ __launch_bounds__(256, 2)
void gemm_nt(const unsigned short* __restrict__ A,
             const unsigned short* __restrict__ W,
             const float* __restrict__ bias,
             float* __restrict__ C, int M, int N, int K) {
  __shared__ __attribute__((aligned(16))) unsigned short As[128 * 32];
  __shared__ __attribute__((aligned(16))) unsigned short Bs[128 * 32];
  const int t = threadIdx.x;
  const int w = t >> 6, lane = t & 63;
  const int quad = lane >> 4, l16 = lane & 15;
  const int m0 = blockIdx.y * 128, n0 = blockIdx.x * 128;
  const int wm = (w >> 1) * 64, wn = (w & 1) * 64;   // wave quadrant: 64x64
  f32x4 acc[4][4] = {};

  for (int k0 = 0; k0 < K; k0 += 32) {
    __syncthreads();
#pragma unroll
    for (int j = 0; j < 2; ++j) {      // 8192 B per tile = 2 issues x 256 lanes x 16 B
      int o = (t + 256 * j) * 16;      // byte offset inside tile (row-major [128][32] bf16, 64 B/row)
      int row = o >> 6, cb = o & 63;
      gld16((char*)As + w * 1024 + j * 4096,
            (const char*)(A + (size_t)(m0 + row) * K + k0) + cb);
      gld16((char*)Bs + w * 1024 + j * 4096,
            (const char*)(W + (size_t)(n0 + row) * K + k0) + cb);
    }
    __syncthreads();
    bf16x8 af[4], bfr[4];
#pragma unroll
    for (int i = 0; i < 4; ++i)
      af[i] = lds_frag(As + (wm + i * 16 + l16) * 32 + quad * 8);
#pragma unroll
    for (int j = 0; j < 4; ++j)
      bfr[j] = lds_frag(Bs + (wn + j * 16 + l16) * 32 + quad * 8);
#pragma unroll
    for (int i = 0; i < 4; ++i)
#pragma unroll
      for (int j = 0; j < 4; ++j)
        acc[i][j] = __builtin_amdgcn_mfma_f32_16x16x32_bf16(af[i], bfr[j], acc[i][j], 0, 0, 0);
  }

#pragma unroll
  for (int j = 0; j < 4; ++j) {
    int col = n0 + wn + j * 16 + l16;
    float bv = bias[col];
#pragma unroll
    for (int i = 0; i < 4; ++i)
#pragma unroll
      for (int r = 0; r < 4; ++r) {
        int row = m0 + wm + i * 16 + quad * 4 + r;   // C/D: col=lane&15, row=quad*4+reg
        C[(size_t)row * N + col] = acc[i][j][r] + bv;
      }
  }
}

// ---------------------------------------------------------------- RoPE: Q,K (B,S,D) fp32 -> (B,H,S,HD)
// Qa gets scale*log2e folded in (softmax runs in exp2 domain); Ka/k_out are unscaled.
__global__ void rope_kernel(const float* __restrict__ Qbuf,
                            const float* __restrict__ Kbuf,
                            const float* __restrict__ fc,
                            const float* __restrict__ fs,
                            unsigned short* __restrict__ Qa,
                            unsigned short* __restrict__ Ka,
                            float* __restrict__ k_out) {
  int idx = blockIdx.x * 256 + threadIdx.x;   // (b:1, s:11, h:4, i:6)
  int i = idx & 63;
  int h = (idx >> 6) & (H_ - 1);
  int s = (idx >> 10) & (S_ - 1);
  int b = idx >> 21;
  size_t src = ((size_t)(b * S_ + s)) * D_ + h * HD_ + 2 * i;
  float2 q = *(const float2*)(Qbuf + src);
  float2 k = *(const float2*)(Kbuf + src);
  float c = fc[s * 64 + i], sn = fs[s * 64 + i];
  float qor = q.x * c - q.y * sn, qoi = q.x * sn + q.y * c;
  float kor = k.x * c - k.y * sn, koi = k.x * sn + k.y * c;
  size_t dst = ((size_t)((b * H_ + h) * S_ + s)) * HD_ + 2 * i;
  *(unsigned int*)(Qa + dst) = (unsigned int)f2bf(qor * QSCALE) | ((unsigned int)f2bf(qoi * QSCALE) << 16);
  *(unsigned int*)(Ka + dst) = (unsigned int)f2bf(kor) | ((unsigned int)f2bf(koi) << 16);
  *(float2*)(k_out + dst) = make_float2(kor, koi);
}

// ---------------------------------------------------------------- V: (B,S,D) fp32 -> v_out (B,H,S,HD) fp32 + Vt (B,H,HD,S) bf16
__global__ void vtrans_kernel(const float* __restrict__ Vbuf,
                              float* __restrict__ v_out,
                              unsigned short* __restrict__ Vt) {
  __shared__ float tile[64][33];
  int t = threadIdx.x;
  int s0 = blockIdx.x * 64, d0 = blockIdx.y * 32, bh = blockIdx.z;
  int b = bh >> 4, h = bh & 15;
#pragma unroll
  for (int rr = 0; rr < 8; ++rr) {
    int sl = rr * 8 + (t >> 5), dl = t & 31;
    float v = Vbuf[((size_t)(b * S_ + s0 + sl)) * D_ + h * HD_ + d0 + dl];
    tile[sl][dl] = v;
    v_out[((size_t)(bh * S_ + s0 + sl)) * HD_ + d0 + dl] = v;
  }
  __syncthreads();
#pragma unroll
  for (int rr = 0; rr < 8; ++rr) {
    int dl = rr * 4 + (t >> 6), sl = t & 63;
    Vt[((size_t)(bh * HD_ + d0 + dl)) * S_ + s0 + sl] = f2bf(tile[sl][dl]);
  }
}

// ---------------------------------------------------------------- causal flash attention
// Qa (pre-scaled), Ka: (B,H,S,HD) bf16; Vt: (B,H,HD,S) bf16; Oa: (B,S,D) bf16.
// Block pairs q-tiles (x, 31-x): uniform 33 iterations. K double-buffered, V early-issued.
__global__ __launch_bounds__(256, 2)
void attn_kernel(const unsigned short* __restrict__ Qa,
                 const unsigned short* __restrict__ Ka,
                 const unsigned short* __restrict__ Vt,
                 unsigned short* __restrict__ Oa) {
  __shared__ __attribute__((aligned(16))) unsigned short Qs[64 * 128];
  __shared__ __attribute__((aligned(16))) unsigned short Ks[2][64 * 128];
  __shared__ __attribute__((aligned(16))) unsigned short Vs[128 * 64];   // Vt tile: [d][n]
  __shared__ __attribute__((aligned(16))) unsigned short Ps[4][16 * 64]; // per-wave P (A-layout source)
  const int t = threadIdx.x, w = t >> 6, lane = t & 63;
  const int quad = lane >> 4, l16 = lane & 15;
  const int bh = blockIdx.y;
  const int b = bh >> 4, h = bh & 15;
  const unsigned short* Qp = Qa + (size_t)bh * S_ * HD_;
  const unsigned short* Kp = Ka + (size_t)bh * S_ * HD_;
  const unsigned short* Vp = Vt + (size_t)bh * HD_ * S_;
  const float NEGINF = -__builtin_inff();

  for (int part = 0; part < 2; ++part) {
    const int qt = part ? (31 - (int)blockIdx.x) : (int)blockIdx.x;
    const int q0 = qt * 64;
    __syncthreads();   // all prior-part LDS reads (Qs/Ks[0]/Vs) complete before restage

    // stage Q tile + K[0] into Ks[0]
#pragma unroll
    for (int j = 0; j < 4; ++j) {
      int o = (t + 256 * j) * 16;
      int row = o >> 8, cb = o & 255;
      gld16((char*)Qs + w * 1024 + j * 4096, (const char*)(Qp + (size_t)(q0 + row) * HD_) + cb);
      gld16((char*)Ks[0] + w * 1024 + j * 4096, (const char*)(Kp + (size_t)row * HD_) + cb);
    }

    float m_i[4], l_i[4];
#pragma unroll
    for (int r = 0; r < 4; ++r) { m_i[r] = NEGINF; l_i[r] = 0.f; }
    f32x4 oacc[8] = {};
    bf16x8 qf[4];
    int c = 0;

    for (int nt = 0; nt <= qt; ++nt) {
      __syncthreads();   // K[nt] (and Q on nt==0) resident in all waves; Vs free

      // early-issue V[nt] (consumed after softmax) and prefetch K[nt+1] (consumed next iter)
#pragma unroll
      for (int j = 0; j < 4; ++j) {
        int o = (t + 256 * j) * 16;
        int vrow = o >> 7, vcb = o & 127;
        gld16((char*)Vs + w * 1024 + j * 4096,
              (const char*)(Vp + (size_t)vrow * S_ + nt * 64) + vcb);
      }
      if (nt < qt) {
#pragma unroll
        for (int j = 0; j < 4; ++j) {
          int o = (t + 256 * j) * 16;
          int row = o >> 8, cb = o & 255;
          gld16((char*)Ks[c ^ 1] + w * 1024 + j * 4096,
                (const char*)(Kp + (size_t)((nt + 1) * 64 + row) * HD_) + cb);
        }
      }

      if (nt == 0) {   // Q fragments are loop-invariant: load once per part
#pragma unroll
        for (int kk = 0; kk < 4; ++kk)
          qf[kk] = lds_frag(Qs + (w * 16 + l16) * 128 + kk * 32 + quad * 8);
      }

      // --- S = Q K^T (wave's 16 q rows x 64 keys), already in log2 domain
      f32x4 sacc[4] = {};
      const unsigned short* Kc = Ks[c];
#pragma unroll
      for (int j = 0; j < 4; ++j)
#pragma unroll
        for (int kk = 0; kk < 4; ++kk) {
          bf16x8 kf = lds_frag(Kc + (j * 16 + l16) * 128 + kk * 32 + quad * 8);
          sacc[j] = __builtin_amdgcn_mfma_f32_16x16x32_bf16(qf[kk], kf, sacc[j], 0, 0, 0);
        }

      // --- causal mask (diag tile only) + online softmax (exp2 domain)
      const int srow_base = q0 + w * 16 + quad * 4;
      const bool diag = (nt == qt);
      float p[4][4], rowmax[4], rowsum[4], alpha[4];
#pragma unroll
      for (int r = 0; r < 4; ++r) rowmax[r] = NEGINF;
#pragma unroll
      for (int j = 0; j < 4; ++j) {
        int scol = nt * 64 + j * 16 + l16;
#pragma unroll
        for (int r = 0; r < 4; ++r) {
          float v = sacc[j][r];
          if (diag && scol > srow_base + r) v = NEGINF;
          p[j][r] = v;
          rowmax[r] = fmaxf(rowmax[r], v);
        }
      }
#pragma unroll
      for (int off = 1; off < 16; off <<= 1)
#pragma unroll
        for (int r = 0; r < 4; ++r) rowmax[r] = fmaxf(rowmax[r], __shfl_xor(rowmax[r], off));
#pragma unroll
      for (int r = 0; r < 4; ++r) {
        float mnew = fmaxf(m_i[r], rowmax[r]);
        alpha[r] = __builtin_amdgcn_exp2f(m_i[r] - mnew);   // first tile: exp2(-inf)=0
        m_i[r] = mnew;
        rowsum[r] = 0.f;
      }
#pragma unroll
      for (int j = 0; j < 4; ++j)
#pragma unroll
        for (int r = 0; r < 4; ++r) {
          float e = __builtin_amdgcn_exp2f(p[j][r] - m_i[r]);   // masked: exp2(-inf)=0
          p[j][r] = e;
          rowsum[r] += e;
        }
#pragma unroll
      for (int off = 1; off < 16; off <<= 1)
#pragma unroll
        for (int r = 0; r < 4; ++r) rowsum[r] += __shfl_xor(rowsum[r], off);
#pragma unroll
      for (int r = 0; r < 4; ++r) l_i[r] = l_i[r] * alpha[r] + rowsum[r];
#pragma unroll
      for (int f = 0; f < 8; ++f)
#pragma unroll
        for (int r = 0; r < 4; ++r) oacc[f][r] *= alpha[r];

      __syncthreads();   // V[nt] resident in all waves (had QK+softmax to land)

      // --- P: C-layout regs -> per-wave LDS (bf16) -> A-layout frags
      unsigned short* Pw = &Ps[w][0];
#pragma unroll
      for (int j = 0; j < 4; ++j)
#pragma unroll
        for (int r = 0; r < 4; ++r)
          Pw[(quad * 4 + r) * 64 + j * 16 + l16] = f2bf(p[j][r]);
      asm volatile("s_waitcnt lgkmcnt(0)" ::: "memory");  // per-wave RAW on Ps

      // --- O += P V  (2 k-steps over 64 keys x 8 d-fragments)
#pragma unroll
      for (int s2 = 0; s2 < 2; ++s2) {
        bf16x8 pf = lds_frag(Pw + l16 * 64 + s2 * 32 + quad * 8);
#pragma unroll
        for (int f = 0; f < 8; ++f) {
          bf16x8 vf = lds_frag(Vs + (f * 16 + l16) * 64 + s2 * 32 + quad * 8);
          oacc[f] = __builtin_amdgcn_mfma_f32_16x16x32_bf16(pf, vf, oacc[f], 0, 0, 0);
        }
      }
      c ^= 1;
    }

    // epilogue: O / l -> bf16 (B,S,D)
    float invl[4];
#pragma unroll
    for (int r = 0; r < 4; ++r) invl[r] = 1.f / l_i[r];
#pragma unroll
    for (int f = 0; f < 8; ++f)
#pragma unroll
      for (int r = 0; r < 4; ++r) {
        int srow = q0 + w * 16 + quad * 4 + r;
        int d = f * 16 + l16;
        Oa[((size_t)(b * S_ + srow)) * D_ + h * HD_ + d] = f2bf(oacc[f][r] * invl[r]);
      }
  }
}

// ----------------------------------------------------------------
extern "C" void kernel_launch(void* const* d_in, const int* in_sizes, int n_in,
                              void* d_out, int out_size, void* d_ws, size_t ws_size,
                              hipStream_t stream) {
  const float* x    = (const float*)d_in[0];
  const float* wq_w = (const float*)d_in[1];
  const float* wq_b = (const float*)d_in[2];
  const float* wk_w = (const float*)d_in[3];
  const float* wk_b = (const float*)d_in[4];
  const float* wv_w = (const float*)d_in[5];
  const float* wv_b = (const float*)d_in[6];
  const float* wo_w = (const float*)d_in[7];
  const float* wo_b = (const float*)d_in[8];
  const float* fc   = (const float*)d_in[9];
  const float* fs   = (const float*)d_in[10];

  float* out = (float*)d_out;
  const size_t BSD = (size_t)B_ * S_ * D_;   // 8388608
  float* k_out = out + BSD;
  float* v_out = out + 2 * BSD;

  // workspace layout (151 MB total)
  char* ws = (char*)d_ws;
  unsigned short* xb   = (unsigned short*)(ws);              // x bf16          16.78 MB
  unsigned short* wqb  = (unsigned short*)(ws + 16777216);   // wq bf16          8.39 MB
  unsigned short* wkb  = (unsigned short*)(ws + 25165824);
  unsigned short* wvb  = (unsigned short*)(ws + 33554432);
  unsigned short* wob  = (unsigned short*)(ws + 41943040);
  float*          Vbuf = (float*)(ws + 50331648);            // V fp32 (B,S,D)  33.55 MB
  unsigned short* Qat  = (unsigned short*)(ws + 83886080);   // Q roped bf16 (B,H,S,HD), pre-scaled
  unsigned short* Kat  = (unsigned short*)(ws + 100663296);  // K roped bf16 (B,H,S,HD)
  unsigned short* Vt   = (unsigned short*)(ws + 117440512);  // V bf16 (B,H,HD,S)
  unsigned short* Ab   = (unsigned short*)(ws + 134217728);  // attn out bf16 (B,S,D)

  // fp32 Q/K intermediates borrow d_out regions (consumed before those regions' final writes)
  float* Qbuf = out;     // overwritten by final gemm (last)
  float* Kbuf = v_out;   // overwritten by vtrans (after rope consumed it)

  cvt_bf16<<<8192, 256, 0, stream>>>(x, xb, 2097152);
  cvt_bf16<<<4096, 256, 0, stream>>>(wq_w, wqb, 1048576);
  cvt_bf16<<<4096, 256, 0, stream>>>(wk_w, wkb, 1048576);
  cvt_bf16<<<4096, 256, 0, stream>>>(wv_w, wvb, 1048576);
  cvt_bf16<<<4096, 256, 0, stream>>>(wo_w, wob, 1048576);

  dim3 gg(16, 32);  // (N/128, M/128)
  gemm_nt<<<gg, 256, 0, stream>>>(xb, wqb, wq_b, Qbuf, 4096, 2048, 2048);
  gemm_nt<<<gg, 256, 0, stream>>>(xb, wkb, wk_b, Kbuf, 4096, 2048, 2048);
  gemm_nt<<<gg, 256, 0, stream>>>(xb, wvb, wv_b, Vbuf, 4096, 2048, 2048);

  rope_kernel<<<16384, 256, 0, stream>>>(Qbuf, Kbuf, fc, fs, Qat, Kat, k_out);
  vtrans_kernel<<<dim3(32, 4, 32), 256, 0, stream>>>(Vbuf, v_out, Vt);
  attn_kernel<<<dim3(16, 32), 256, 0, stream>>>(Qat, Kat, Vt, Ab);
  gemm_nt<<<gg, 256, 0, stream>>>(Ab, wob, wo_b, out, 4096, 2048, 2048);
}

// Round 3
// 539.880 us; speedup vs baseline: 1.3353x; 1.0409x over previous
//
#include <hip/hip_runtime.h>

// Problem constants
#define B_  2
#define S_  2048
#define D_  2048
#define H_  16
#define HD_ 128

// 1/sqrt(128) * log2(e): fold softmax scale AND exp->exp2 conversion into Q
#define QSCALE 0.1275174319003887f

typedef __attribute__((ext_vector_type(4))) float  f32x4;
typedef __attribute__((ext_vector_type(8))) short  short8;
typedef __attribute__((ext_vector_type(8))) __bf16 bf16x8;
typedef __attribute__((ext_vector_type(4))) float  floatv4;
typedef __attribute__((ext_vector_type(4))) unsigned short ushortv4;

// fp32 -> bf16 bits, round-to-nearest-even
__device__ inline unsigned short f2bf(float f) {
  unsigned int u = __builtin_bit_cast(unsigned int, f);
  u += 0x7fffu + ((u >> 16) & 1u);
  return (unsigned short)(u >> 16);
}

// async global->LDS, 16B per lane. lds must be wave-uniform base; data lands at base + lane*16.
__device__ inline void gld16(void* lds, const void* g) {
  __builtin_amdgcn_global_load_lds(
      (const __attribute__((address_space(1))) unsigned int*)g,
      (__attribute__((address_space(3))) unsigned int*)lds, 16, 0, 0);
}

__device__ inline bf16x8 lds_frag(const unsigned short* p) {
  return __builtin_bit_cast(bf16x8, *(const short8*)p);
}

// ---------------------------------------------------------------- fused converts (x + 4 weights)
__global__ void cvt_all(const float* __restrict__ x,
                        const float* __restrict__ w0, const float* __restrict__ w1,
                        const float* __restrict__ w2, const float* __restrict__ w3,
                        unsigned short* __restrict__ xb,
                        unsigned short* __restrict__ wb0, unsigned short* __restrict__ wb1,
                        unsigned short* __restrict__ wb2, unsigned short* __restrict__ wb3) {
  int i = blockIdx.x * 256 + threadIdx.x;   // quad index, total 6291456
  const float* s; unsigned short* d; int off;
  if (i < 2097152) { s = x; d = xb; off = i; }
  else {
    int j = i - 2097152;
    int r = j >> 20; off = j & 1048575;
    s = (r == 0) ? w0 : (r == 1) ? w1 : (r == 2) ? w2 : w3;
    d = (r == 0) ? wb0 : (r == 1) ? wb1 : (r == 2) ? wb2 : wb3;
  }
  floatv4 v = ((const floatv4*)s)[off];
  ushortv4 o;
  o.x = f2bf(v.x); o.y = f2bf(v.y); o.z = f2bf(v.z); o.w = f2bf(v.w);
  ((ushortv4*)d)[off] = o;
}

// ---------------------------------------------------------------- GEMM (NT): C[m][n] = sum_k A[m][k]*W[n][k] + bias[n]
__global__ __launch_bounds__(256, 2)
void gemm_nt(const unsigned short* __restrict__ A,
             const unsigned short* __restrict__ W,
             const float* __restrict__ bias,
             float* __restrict__ C, int M, int N, int K) {
  __shared__ __attribute__((aligned(16))) unsigned short As[128 * 32];
  __shared__ __attribute__((aligned(16))) unsigned short Bs[128 * 32];
  const int t = threadIdx.x;
  const int w = t >> 6, lane = t & 63;
  const int quad = lane >> 4, l16 = lane & 15;
  const int m0 = blockIdx.y * 128, n0 = blockIdx.x * 128;
  const int wm = (w >> 1) * 64, wn = (w & 1) * 64;   // wave quadrant: 64x64
  f32x4 acc[4][4] = {};

  for (int k0 = 0; k0 < K; k0 += 32) {
    __syncthreads();
#pragma unroll
    for (int j = 0; j < 2; ++j) {      // 8192 B per tile = 2 issues x 256 lanes x 16 B
      int o = (t + 256 * j) * 16;      // byte offset inside tile (row-major [128][32] bf16, 64 B/row)
      int row = o >> 6, cb = o & 63;
      gld16((char*)As + w * 1024 + j * 4096,
            (const char*)(A + (size_t)(m0 + row) * K + k0) + cb);
      gld16((char*)Bs + w * 1024 + j * 4096,
            (const char*)(W + (size_t)(n0 + row) * K + k0) + cb);
    }
    __syncthreads();
    bf16x8 af[4], bfr[4];
#pragma unroll
    for (int i = 0; i < 4; ++i)
      af[i] = lds_frag(As + (wm + i * 16 + l16) * 32 + quad * 8);
#pragma unroll
    for (int j = 0; j < 4; ++j)
      bfr[j] = lds_frag(Bs + (wn + j * 16 + l16) * 32 + quad * 8);
#pragma unroll
    for (int i = 0; i < 4; ++i)
#pragma unroll
      for (int j = 0; j < 4; ++j)
        acc[i][j] = __builtin_amdgcn_mfma_f32_16x16x32_bf16(af[i], bfr[j], acc[i][j], 0, 0, 0);
  }

#pragma unroll
  for (int j = 0; j < 4; ++j) {
    int col = n0 + wn + j * 16 + l16;
    float bv = bias[col];
#pragma unroll
    for (int i = 0; i < 4; ++i)
#pragma unroll
      for (int r = 0; r < 4; ++r) {
        int row = m0 + wm + i * 16 + quad * 4 + r;   // C/D: col=lane&15, row=quad*4+reg
        C[(size_t)row * N + col] = acc[i][j][r] + bv;
      }
  }
}

// ---------------------------------------------------------------- RoPE: Q,K (B,S,D) fp32 -> (B,H,S,HD)
// Qa gets scale*log2e folded in (softmax runs in exp2 domain); Ka/k_out are unscaled.
__global__ void rope_kernel(const float* __restrict__ Qbuf,
                            const float* __restrict__ Kbuf,
                            const float* __restrict__ fc,
                            const float* __restrict__ fs,
                            unsigned short* __restrict__ Qa,
                            unsigned short* __restrict__ Ka,
                            float* __restrict__ k_out) {
  int idx = blockIdx.x * 256 + threadIdx.x;   // (b:1, s:11, h:4, i:6)
  int i = idx & 63;
  int h = (idx >> 6) & (H_ - 1);
  int s = (idx >> 10) & (S_ - 1);
  int b = idx >> 21;
  size_t src = ((size_t)(b * S_ + s)) * D_ + h * HD_ + 2 * i;
  float2 q = *(const float2*)(Qbuf + src);
  float2 k = *(const float2*)(Kbuf + src);
  float c = fc[s * 64 + i], sn = fs[s * 64 + i];
  float qor = q.x * c - q.y * sn, qoi = q.x * sn + q.y * c;
  float kor = k.x * c - k.y * sn, koi = k.x * sn + k.y * c;
  size_t dst = ((size_t)((b * H_ + h) * S_ + s)) * HD_ + 2 * i;
  *(unsigned int*)(Qa + dst) = (unsigned int)f2bf(qor * QSCALE) | ((unsigned int)f2bf(qoi * QSCALE) << 16);
  *(unsigned int*)(Ka + dst) = (unsigned int)f2bf(kor) | ((unsigned int)f2bf(koi) << 16);
  *(float2*)(k_out + dst) = make_float2(kor, koi);
}

// ---------------------------------------------------------------- V: (B,S,D) fp32 -> v_out (B,H,S,HD) fp32 + Vt (B,H,HD,S) bf16
__global__ void vtrans_kernel(const float* __restrict__ Vbuf,
                              float* __restrict__ v_out,
                              unsigned short* __restrict__ Vt) {
  __shared__ float tile[64][33];
  int t = threadIdx.x;
  int s0 = blockIdx.x * 64, d0 = blockIdx.y * 32, bh = blockIdx.z;
  int b = bh >> 4, h = bh & 15;
#pragma unroll
  for (int rr = 0; rr < 8; ++rr) {
    int sl = rr * 8 + (t >> 5), dl = t & 31;
    float v = Vbuf[((size_t)(b * S_ + s0 + sl)) * D_ + h * HD_ + d0 + dl];
    tile[sl][dl] = v;
    v_out[((size_t)(bh * S_ + s0 + sl)) * HD_ + d0 + dl] = v;
  }
  __syncthreads();
#pragma unroll
  for (int rr = 0; rr < 8; ++rr) {
    int dl = rr * 4 + (t >> 6), sl = t & 63;
    Vt[((size_t)(bh * HD_ + d0 + dl)) * S_ + s0 + sl] = f2bf(tile[sl][dl]);
  }
}

// ---------------------------------------------------------------- causal flash attention
// Qa (pre-scaled), Ka: (B,H,S,HD) bf16; Vt: (B,H,HD,S) bf16; Oa: (B,S,D) bf16.
// 128 q-rows/block, 32 rows/wave. Q direct global->VGPR. K double-buffered:
// V issued at top (drained by mid barrier), K[nt+1] issued after mid barrier
// (drained by next top barrier) — neither barrier waits on a fresh load.
__global__ __launch_bounds__(256, 2)
void attn_kernel(const unsigned short* __restrict__ Qa,
                 const unsigned short* __restrict__ Ka,
                 const unsigned short* __restrict__ Vt,
                 unsigned short* __restrict__ Oa) {
  __shared__ __attribute__((aligned(16))) unsigned short Ks[2][64 * 128]; // 32 KB
  __shared__ __attribute__((aligned(16))) unsigned short Vs[128 * 64];    // 16 KB  [d][n]
  __shared__ __attribute__((aligned(16))) unsigned short Ps[4][32 * 64];  // 16 KB  per-wave P
  const int t = threadIdx.x, w = t >> 6, lane = t & 63;
  const int quad = lane >> 4, l16 = lane & 15;
  const int bh = blockIdx.y, b = bh >> 4, h = bh & 15;
  const unsigned short* Qp = Qa + (size_t)bh * S_ * HD_;
  const unsigned short* Kp = Ka + (size_t)bh * S_ * HD_;
  const unsigned short* Vp = Vt + (size_t)bh * HD_ * S_;
  const float NEGINF = -__builtin_inff();

  for (int part = 0; part < 2; ++part) {
    const int qt = part ? (15 - (int)blockIdx.x) : (int)blockIdx.x;
    const int q0 = qt * 128;
    const int ntmax = 2 * qt + 1;

    __syncthreads();   // prior part's LDS reads fully done before restage

    // stage K[0]
#pragma unroll
    for (int j = 0; j < 4; ++j) {
      int o = (t + 256 * j) * 16;
      int row = o >> 8, cb = o & 255;
      gld16((char*)Ks[0] + w * 1024 + j * 4096, (const char*)(Kp + (size_t)row * HD_) + cb);
    }
    // Q fragments: loop-invariant, straight from global (16B/lane, 64B runs per row)
    bf16x8 qf[2][4];
#pragma unroll
    for (int mi = 0; mi < 2; ++mi)
#pragma unroll
      for (int kk = 0; kk < 4; ++kk)
        qf[mi][kk] = *(const bf16x8*)(Qp + (size_t)(q0 + w * 32 + mi * 16 + l16) * HD_ + kk * 32 + quad * 8);

    float m_i[2][4], l_i[2][4];
#pragma unroll
    for (int mi = 0; mi < 2; ++mi)
#pragma unroll
      for (int r = 0; r < 4; ++r) { m_i[mi][r] = NEGINF; l_i[mi][r] = 0.f; }
    f32x4 oacc[2][8] = {};
    int c = 0;

    for (int nt = 0; nt <= ntmax; ++nt) {
      __syncthreads();   // K[c] (+ V-free) resident; drains K prefetch issued last iter

      // early-issue V[nt]: consumed only after softmax (mid barrier)
#pragma unroll
      for (int j = 0; j < 4; ++j) {
        int o = (t + 256 * j) * 16;
        int vrow = o >> 7, vcb = o & 127;
        gld16((char*)Vs + w * 1024 + j * 4096,
              (const char*)(Vp + (size_t)vrow * S_ + nt * 64) + vcb);
      }

      // --- S = Q K^T: wave's 32 q-rows x 64 keys (log2 domain)
      f32x4 sacc[2][4] = {};
      const unsigned short* Kc = Ks[c];
#pragma unroll
      for (int j = 0; j < 4; ++j)
#pragma unroll
        for (int kk = 0; kk < 4; ++kk) {
          bf16x8 kf = lds_frag(Kc + (j * 16 + l16) * 128 + kk * 32 + quad * 8);
          sacc[0][j] = __builtin_amdgcn_mfma_f32_16x16x32_bf16(qf[0][kk], kf, sacc[0][j], 0, 0, 0);
          sacc[1][j] = __builtin_amdgcn_mfma_f32_16x16x32_bf16(qf[1][kk], kf, sacc[1][j], 0, 0, 0);
        }

      // --- causal mask (last two tiles only) + online softmax (exp2 domain), in-place in sacc
      const bool dotail = (nt >= 2 * qt);
      float rowmax[2][4], alpha[2][4], rowsum[2][4];
#pragma unroll
      for (int mi = 0; mi < 2; ++mi)
#pragma unroll
        for (int r = 0; r < 4; ++r) rowmax[mi][r] = NEGINF;
#pragma unroll
      for (int mi = 0; mi < 2; ++mi)
#pragma unroll
        for (int j = 0; j < 4; ++j) {
          int scol = nt * 64 + j * 16 + l16;
#pragma unroll
          for (int r = 0; r < 4; ++r) {
            float v = sacc[mi][j][r];
            if (dotail && scol > q0 + w * 32 + mi * 16 + quad * 4 + r) v = NEGINF;
            sacc[mi][j][r] = v;
            rowmax[mi][r] = fmaxf(rowmax[mi][r], v);
          }
        }
#pragma unroll
      for (int off = 1; off < 16; off <<= 1)
#pragma unroll
        for (int mi = 0; mi < 2; ++mi)
#pragma unroll
          for (int r = 0; r < 4; ++r)
            rowmax[mi][r] = fmaxf(rowmax[mi][r], __shfl_xor(rowmax[mi][r], off));
#pragma unroll
      for (int mi = 0; mi < 2; ++mi)
#pragma unroll
        for (int r = 0; r < 4; ++r) {
          float mnew = fmaxf(m_i[mi][r], rowmax[mi][r]);
          alpha[mi][r] = __builtin_amdgcn_exp2f(m_i[mi][r] - mnew);   // first tile: exp2(-inf)=0
          m_i[mi][r] = mnew;
          rowsum[mi][r] = 0.f;
        }
#pragma unroll
      for (int mi = 0; mi < 2; ++mi)
#pragma unroll
        for (int j = 0; j < 4; ++j)
#pragma unroll
          for (int r = 0; r < 4; ++r) {
            float e = __builtin_amdgcn_exp2f(sacc[mi][j][r] - m_i[mi][r]);  // masked: exp2(-inf)=0
            sacc[mi][j][r] = e;
            rowsum[mi][r] += e;
          }
#pragma unroll
      for (int off = 1; off < 16; off <<= 1)
#pragma unroll
        for (int mi = 0; mi < 2; ++mi)
#pragma unroll
          for (int r = 0; r < 4; ++r)
            rowsum[mi][r] += __shfl_xor(rowsum[mi][r], off);
#pragma unroll
      for (int mi = 0; mi < 2; ++mi)
#pragma unroll
        for (int r = 0; r < 4; ++r) l_i[mi][r] = l_i[mi][r] * alpha[mi][r] + rowsum[mi][r];
#pragma unroll
      for (int mi = 0; mi < 2; ++mi)
#pragma unroll
        for (int f = 0; f < 8; ++f)
#pragma unroll
          for (int r = 0; r < 4; ++r) oacc[mi][f][r] *= alpha[mi][r];

      __syncthreads();   // V[nt] resident (drain covered by QK+softmax work)

      // prefetch K[nt+1] AFTER mid barrier: drained at NEXT top barrier (covered by PV)
      if (nt < ntmax) {
#pragma unroll
        for (int j = 0; j < 4; ++j) {
          int o = (t + 256 * j) * 16;
          int row = o >> 8, cb = o & 255;
          gld16((char*)Ks[c ^ 1] + w * 1024 + j * 4096,
                (const char*)(Kp + (size_t)((nt + 1) * 64 + row) * HD_) + cb);
        }
      }

      // --- P: C-layout regs -> per-wave LDS (bf16) -> A-layout frags
      unsigned short* Pw = &Ps[w][0];
#pragma unroll
      for (int mi = 0; mi < 2; ++mi)
#pragma unroll
        for (int j = 0; j < 4; ++j)
#pragma unroll
          for (int r = 0; r < 4; ++r)
            Pw[(mi * 16 + quad * 4 + r) * 64 + j * 16 + l16] = f2bf(sacc[mi][j][r]);
      asm volatile("s_waitcnt lgkmcnt(0)" ::: "memory");  // per-wave RAW on Ps

      // --- O += P V  (2 k-steps over 64 keys x 8 d-fragments, 2 row-blocks)
#pragma unroll
      for (int s2 = 0; s2 < 2; ++s2) {
        bf16x8 pf0 = lds_frag(Pw + (l16) * 64 + s2 * 32 + quad * 8);
        bf16x8 pf1 = lds_frag(Pw + (16 + l16) * 64 + s2 * 32 + quad * 8);
#pragma unroll
        for (int f = 0; f < 8; ++f) {
          bf16x8 vf = lds_frag(Vs + (f * 16 + l16) * 64 + s2 * 32 + quad * 8);
          oacc[0][f] = __builtin_amdgcn_mfma_f32_16x16x32_bf16(pf0, vf, oacc[0][f], 0, 0, 0);
          oacc[1][f] = __builtin_amdgcn_mfma_f32_16x16x32_bf16(pf1, vf, oacc[1][f], 0, 0, 0);
        }
      }
      c ^= 1;
    }

    // epilogue: O / l -> bf16 (B,S,D)
#pragma unroll
    for (int mi = 0; mi < 2; ++mi) {
      float invl[4];
#pragma unroll
      for (int r = 0; r < 4; ++r) invl[r] = 1.f / l_i[mi][r];
#pragma unroll
      for (int f = 0; f < 8; ++f)
#pragma unroll
        for (int r = 0; r < 4; ++r) {
          int srow = q0 + w * 32 + mi * 16 + quad * 4 + r;
          int d = f * 16 + l16;
          Oa[((size_t)(b * S_ + srow)) * D_ + h * HD_ + d] = f2bf(oacc[mi][f][r] * invl[r]);
        }
    }
  }
}

// ----------------------------------------------------------------
extern "C" void kernel_launch(void* const* d_in, const int* in_sizes, int n_in,
                              void* d_out, int out_size, void* d_ws, size_t ws_size,
                              hipStream_t stream) {
  const float* x    = (const float*)d_in[0];
  const float* wq_w = (const float*)d_in[1];
  const float* wq_b = (const float*)d_in[2];
  const float* wk_w = (const float*)d_in[3];
  const float* wk_b = (const float*)d_in[4];
  const float* wv_w = (const float*)d_in[5];
  const float* wv_b = (const float*)d_in[6];
  const float* wo_w = (const float*)d_in[7];
  const float* wo_b = (const float*)d_in[8];
  const float* fc   = (const float*)d_in[9];
  const float* fs   = (const float*)d_in[10];

  float* out = (float*)d_out;
  const size_t BSD = (size_t)B_ * S_ * D_;   // 8388608
  float* k_out = out + BSD;
  float* v_out = out + 2 * BSD;

  // workspace layout (151 MB total)
  char* ws = (char*)d_ws;
  unsigned short* xb   = (unsigned short*)(ws);              // x bf16          16.78 MB
  unsigned short* wqb  = (unsigned short*)(ws + 16777216);   // wq bf16          8.39 MB
  unsigned short* wkb  = (unsigned short*)(ws + 25165824);
  unsigned short* wvb  = (unsigned short*)(ws + 33554432);
  unsigned short* wob  = (unsigned short*)(ws + 41943040);
  float*          Vbuf = (float*)(ws + 50331648);            // V fp32 (B,S,D)  33.55 MB
  unsigned short* Qat  = (unsigned short*)(ws + 83886080);   // Q roped bf16 (B,H,S,HD), pre-scaled
  unsigned short* Kat  = (unsigned short*)(ws + 100663296);  // K roped bf16 (B,H,S,HD)
  unsigned short* Vt   = (unsigned short*)(ws + 117440512);  // V bf16 (B,H,HD,S)
  unsigned short* Ab   = (unsigned short*)(ws + 134217728);  // attn out bf16 (B,S,D)

  // fp32 Q/K intermediates borrow d_out regions (consumed before those regions' final writes)
  float* Qbuf = out;     // overwritten by final gemm (last)
  float* Kbuf = v_out;   // overwritten by vtrans (after rope consumed it)

  cvt_all<<<24576, 256, 0, stream>>>(x, wq_w, wk_w, wv_w, wo_w, xb, wqb, wkb, wvb, wob);

  dim3 gg(16, 32);  // (N/128, M/128)
  gemm_nt<<<gg, 256, 0, stream>>>(xb, wqb, wq_b, Qbuf, 4096, 2048, 2048);
  gemm_nt<<<gg, 256, 0, stream>>>(xb, wkb, wk_b, Kbuf, 4096, 2048, 2048);
  gemm_nt<<<gg, 256, 0, stream>>>(xb, wvb, wv_b, Vbuf, 4096, 2048, 2048);

  rope_kernel<<<16384, 256, 0, stream>>>(Qbuf, Kbuf, fc, fs, Qat, Kat, k_out);
  vtrans_kernel<<<dim3(32, 4, 32), 256, 0, stream>>>(Vbuf, v_out, Vt);
  attn_kernel<<<dim3(8, 32), 256, 0, stream>>>(Qat, Kat, Vt, Ab);
  gemm_nt<<<gg, 256, 0, stream>>>(Ab, wob, wo_b, out, 4096, 2048, 2048);
}